// Round 1
// baseline (7519.105 us; speedup 1.0000x reference)
//
#include <hip/hip_runtime.h>
#include <math.h>

// ---------------------------------------------------------------------------
// TDS decoder: 200-step GRU + attention decode, single persistent kernel.
//
// Grid = 256 blocks x 256 threads (1 block/CU on MI355X; all co-resident).
// Cross-block handshake per step:
//   - every block:  arrive = fetch_add(release)        (all -> block0)
//   - block 0:      decide (out logits, argmax, zero next-parity accum),
//                   then flag = store(release)          (block0 -> all)
// All cross-block data reads are relaxed AGENT-scope atomic loads (sc1 ->
// coherence point, no buffer_inv), so per-block key/value slices stay hot in
// the local XCD L2 for all 200 steps.
// Workspace: ~260 KiB of d_ws. Init kernel resets control region every call.
// ---------------------------------------------------------------------------

#define NV      40
#define HDIM    512
#define TENC    8192
#define MAXLEN  200
#define EOS_IDX 38
#define NB      256
#define NT      256
#define ROWS    (TENC / NB)   /* 32 attention rows per block  */
#define GHR     (1536 / NB)   /* 6 W_hh rows per block        */
#define NG      16            /* out-logit accumulator groups */
#define SCALE   0.04419417382415922f  /* 1/sqrt(512) */

// ws layout (float indices)
#define WS_FLAG    0     /* int:   decided-step count; -1 until prologue done */
#define WS_ARRIVE  16    /* int:   cumulative arrivals                        */
#define WS_BEST    32    /* int:   last argmax token (init EOS)               */
#define WS_S       64    /* float[2]: softmax denominator, ping-pong          */
#define WS_OUTACC  128   /* float[2][NG][NV]: out-logit partials, ping-pong   */
#define WS_GH      2048  /* float[2][1536]: W_hh @ h + b_hh, ping-pong        */
#define WS_GI      5120  /* float[40*1536]: W_ih @ embed[v] + b_ih            */
// end: 5120 + 61440 = 66560 floats  (~260 KiB)

__device__ __forceinline__ int ld_ai(int* p) {
  return __hip_atomic_load(p, __ATOMIC_RELAXED, __HIP_MEMORY_SCOPE_AGENT);
}
__device__ __forceinline__ float ld_af(float* p) {
  return __hip_atomic_load(p, __ATOMIC_RELAXED, __HIP_MEMORY_SCOPE_AGENT);
}
__device__ __forceinline__ void st_af(float* p, float v) {
  __hip_atomic_store(p, v, __ATOMIC_RELAXED, __HIP_MEMORY_SCOPE_AGENT);
}
__device__ __forceinline__ void st_ai(int* p, int v) {
  __hip_atomic_store(p, v, __ATOMIC_RELAXED, __HIP_MEMORY_SCOPE_AGENT);
}

__device__ __forceinline__ float wred(float s) {
#pragma unroll
  for (int o = 32; o > 0; o >>= 1) s += __shfl_xor(s, o, 64);
  return s;
}

// full-wave dot product of two 512-float vectors (a: global, b: global/LDS)
__device__ __forceinline__ float wdot512(const float* __restrict__ a,
                                         const float* __restrict__ b) {
  const int l = threadIdx.x & 63;
  const float4 a0 = ((const float4*)a)[l];
  const float4 a1 = ((const float4*)a)[l + 64];
  const float4 b0 = ((const float4*)b)[l];
  const float4 b1 = ((const float4*)b)[l + 64];
  float s = a0.x * b0.x + a0.y * b0.y + a0.z * b0.z + a0.w * b0.w +
            a1.x * b1.x + a1.y * b1.y + a1.z * b1.z + a1.w * b1.w;
  return wred(s);
}

__global__ void dec_init(int* wsi) {
  const int tid = threadIdx.x;
  for (int k = tid; k < 2048; k += NT) {
    int v = 0;
    if (k == WS_FLAG) v = -1;
    else if (k == WS_BEST) v = EOS_IDX;
    wsi[k] = v;
  }
}

__global__ void __launch_bounds__(NT) dec_main(
    const float* __restrict__ enc, const float* __restrict__ hidden,
    const float* __restrict__ embed, const float* __restrict__ w_ih,
    const float* __restrict__ w_hh, const float* __restrict__ b_ih,
    const float* __restrict__ b_hh, const float* __restrict__ w_out,
    const float* __restrict__ b_out, float* __restrict__ o,
    float* __restrict__ ws) {
  const int b = blockIdx.x, tid = threadIdx.x;
  const int wave = tid >> 6, lane = tid & 63;
  int* wsi = (int*)ws;

  __shared__ __align__(16) float h_lds[HDIM];
  __shared__ float p_lds[ROWS];
  __shared__ __align__(16) float sp_lds[HDIM];
  __shared__ float hp_lds[NV];   // block 0: h-half of out logits + bias
  __shared__ float out_lds[NV];  // block 0: final logits
  __shared__ float sc_lds[2];    // [0]=S_{t-1} for normalize, [1]=S_t decide
  __shared__ int best_lds;

  // ----------------- prologue -----------------
  h_lds[tid] = hidden[tid];
  h_lds[tid + 256] = hidden[tid + 256];

  // gi_all[v][j] = W_ih[j] . embed[v] + b_ih[j]   (240 dots per block)
  for (int u = wave; u < 240; u += 4) {
    const int g = b * 240 + u;
    const int v = g / 1536, j = g - v * 1536;
    const float d = wdot512(w_ih + (size_t)j * 512, embed + (size_t)v * 512);
    if (lane == 0) ws[WS_GI + (size_t)v * 1536 + j] = d + b_ih[j];
  }
  // gh[0][j] = W_hh[j] . h0 + b_hh[j]
  {
    const int j0 = b * GHR;
    for (int jr = wave; jr < GHR; jr += 4) {
      const int j = j0 + jr;
      const float d = wdot512(w_hh + (size_t)j * 512, hidden);
      if (lane == 0) st_af(&ws[WS_GH + j], d + b_hh[j]);
    }
  }
  __syncthreads();
  if (tid == 0)
    __hip_atomic_fetch_add(&wsi[WS_ARRIVE], 1, __ATOMIC_RELEASE,
                           __HIP_MEMORY_SCOPE_AGENT);
  if (b == 0 && tid == 0) {
    while (ld_ai(&wsi[WS_ARRIVE]) < NB) __builtin_amdgcn_s_sleep(1);
    __hip_atomic_store(&wsi[WS_FLAG], 0, __ATOMIC_RELEASE,
                       __HIP_MEMORY_SCOPE_AGENT);
  }

  // ----------------- main loop -----------------
  int eos_reg = MAXLEN;  // block0/tid0 only
  float* attn = o + (size_t)MAXLEN * NV + 1;
  const int r0 = b * ROWS;

  for (int t = 0; t < MAXLEN; ++t) {
    const int par = t & 1, nxt = par ^ 1;

    // wait for step-t inputs (best_{t-1}, gh_{t-1}, S_{t-1} final)
    if (tid == 0) {
      while (ld_ai(&wsi[WS_FLAG]) < t) __builtin_amdgcn_s_sleep(1);
      best_lds = ld_ai(&wsi[WS_BEST]);
      sc_lds[0] = ld_af(&ws[WS_S + ((t - 1) & 1)]);
    }
    __syncthreads();

    // lazily normalize previous step's attention weights (p in LDS)
    if (t > 0 && tid < ROWS) {
      const float invS = 1.0f / sc_lds[0];
      attn[(size_t)(t - 1) * TENC + r0 + tid] = p_lds[tid] * invS;
    }

    // GRU combine: h_t  (redundant per block, 2 elems/thread, into LDS)
    {
      const int best = best_lds;
      const float* gi = ws + WS_GI + (size_t)best * 1536;
      float* ghp = ws + WS_GH + (size_t)par * 1536;
#pragma unroll
      for (int q = 0; q < 2; ++q) {
        const int j = tid + q * 256;
        const float gir = gi[j], giz = gi[j + 512], gin = gi[j + 1024];
        const float ghr = ld_af(&ghp[j]);
        const float ghz = ld_af(&ghp[j + 512]);
        const float ghn = ld_af(&ghp[j + 1024]);
        const float r = 1.0f / (1.0f + expf(-(gir + ghr)));
        const float z = 1.0f / (1.0f + expf(-(giz + ghz)));
        const float n = tanhf(gin + r * ghn);
        h_lds[j] = (1.0f - z) * n + z * h_lds[j];
      }
    }
    __syncthreads();

    // attention logits -> p = exp(logit)   (8 rows per wave)
#pragma unroll
    for (int rr = wave; rr < ROWS; rr += 4) {
      const int row = r0 + rr;
      const float d = wdot512(enc + (size_t)row * 1024, h_lds);
      const float p = expf(d * SCALE);
      if (lane == 0) p_lds[rr] = p;
    }
    // gh_t = W_hh @ h_t + b_hh  (for step t+1)
    {
      const int j0 = b * GHR;
      for (int jr = wave; jr < GHR; jr += 4) {
        const int j = j0 + jr;
        const float d = wdot512(w_hh + (size_t)j * 512, h_lds);
        if (lane == 0) st_af(&ws[WS_GH + nxt * 1536 + j], d + b_hh[j]);
      }
    }
    // block 0: h-half of out logits  hp[v] = W_out[v][512:] . h + b_out[v]
    if (b == 0) {
      for (int v = wave; v < NV; v += 4) {
        const float d = wdot512(w_out + (size_t)v * 1024 + 512, h_lds);
        if (lane == 0) hp_lds[v] = d + b_out[v];
      }
    }
    __syncthreads();

    // S partial (one atomic per block)
    if (tid == 0) {
      float s = 0.0f;
#pragma unroll
      for (int i = 0; i < ROWS; ++i) s += p_lds[i];
      atomicAdd(&ws[WS_S + par], s);
    }
    // value pass: sp[d] = sum_i p_i * V[i][d]  (thread owns cols tid, tid+256)
    {
      const float* vbase = enc + 512 + (size_t)r0 * 1024;
      float a0 = 0.0f, a1 = 0.0f;
#pragma unroll 8
      for (int i = 0; i < ROWS; ++i) {
        const float p = p_lds[i];
        a0 += p * vbase[(size_t)i * 1024 + tid];
        a1 += p * vbase[(size_t)i * 1024 + tid + 256];
      }
      sp_lds[tid] = a0;
      sp_lds[tid + 256] = a1;
    }
    __syncthreads();

    // fold partial summary through W_out[:, :512]: 40 atomics per block
    {
      float* acc = ws + WS_OUTACC + par * (NG * NV) + (b & (NG - 1)) * NV;
      for (int v = wave; v < NV; v += 4) {
        const float d = wdot512(w_out + (size_t)v * 1024, sp_lds);
        if (lane == 0) atomicAdd(&acc[v], d);
      }
    }
    __syncthreads();  // drains all stores/atomics (vmcnt 0) before arrive

    if (tid == 0)
      __hip_atomic_fetch_add(&wsi[WS_ARRIVE], 1, __ATOMIC_RELEASE,
                             __HIP_MEMORY_SCOPE_AGENT);

    // ----------------- decide (block 0) -----------------
    if (b == 0) {
      if (tid == 0) {
        const int target = NB * (t + 2);
        while (ld_ai(&wsi[WS_ARRIVE]) < target) __builtin_amdgcn_s_sleep(1);
        sc_lds[1] = ld_af(&ws[WS_S + par]);
      }
      __syncthreads();
      if (tid < NV) {
        float s = 0.0f;
        float* acc = ws + WS_OUTACC + par * (NG * NV);
#pragma unroll
        for (int g = 0; g < NG; ++g) s += ld_af(&acc[g * NV + tid]);
        const float ov = s * (1.0f / sc_lds[1]) + hp_lds[tid];
        out_lds[tid] = ov;
        o[(size_t)t * NV + tid] = ov;
      }
      // zero next-parity accumulators (write-through so remote RMWs see them)
      {
        float* accn = ws + WS_OUTACC + nxt * (NG * NV);
        for (int k = tid; k < NG * NV; k += NT) st_af(&accn[k], 0.0f);
        if (tid == 0) st_af(&ws[WS_S + nxt], 0.0f);
      }
      __syncthreads();
      if (tid == 0) {
        float bv = out_lds[0];
        int bi = 0;
#pragma unroll
        for (int v = 1; v < NV; ++v) {
          const float x = out_lds[v];
          if (x > bv) { bv = x; bi = v; }
        }
        st_ai(&wsi[WS_BEST], bi);
        if (bi == EOS_IDX && eos_reg == MAXLEN) eos_reg = t;
        if (t == MAXLEN - 1) o[(size_t)MAXLEN * NV] = (float)eos_reg;
        __hip_atomic_store(&wsi[WS_FLAG], t + 1, __ATOMIC_RELEASE,
                           __HIP_MEMORY_SCOPE_AGENT);
      }
    }
  }

  // final lazy normalize of step-199 attention weights
  if (tid == 0) {
    while (ld_ai(&wsi[WS_FLAG]) < MAXLEN) __builtin_amdgcn_s_sleep(1);
    sc_lds[0] = ld_af(&ws[WS_S + ((MAXLEN - 1) & 1)]);
  }
  __syncthreads();
  if (tid < ROWS) {
    const float invS = 1.0f / sc_lds[0];
    attn[(size_t)(MAXLEN - 1) * TENC + r0 + tid] = p_lds[tid] * invS;
  }
}

extern "C" void kernel_launch(void* const* d_in, const int* in_sizes, int n_in,
                              void* d_out, int out_size, void* d_ws,
                              size_t ws_size, hipStream_t stream) {
  const float* enc    = (const float*)d_in[0];
  const float* hidden = (const float*)d_in[1];
  const float* embed  = (const float*)d_in[2];
  const float* w_ih   = (const float*)d_in[3];
  const float* w_hh   = (const float*)d_in[4];
  const float* b_ih   = (const float*)d_in[5];
  const float* b_hh   = (const float*)d_in[6];
  const float* w_out  = (const float*)d_in[7];
  const float* b_out  = (const float*)d_in[8];
  float* out = (float*)d_out;
  float* ws  = (float*)d_ws;

  dec_init<<<dim3(1), dim3(NT), 0, stream>>>((int*)d_ws);
  dec_main<<<dim3(NB), dim3(NT), 0, stream>>>(enc, hidden, embed, w_ih, w_hh,
                                              b_ih, b_hh, w_out, b_out, out,
                                              ws);
}

// Round 2
// 4607.113 us; speedup vs baseline: 1.6321x; 1.6321x over previous
//
#include <hip/hip_runtime.h>
#include <math.h>

// ---------------------------------------------------------------------------
// TDS decoder: 200-step GRU + attention decode, single persistent kernel.
// R2: 1024 threads/block (16 waves/CU), ONE global barrier per step,
//     redundant decide in every block, 3-slot rotation for acc/gh,
//     gh prefetch overlapping the decide phase.
// ---------------------------------------------------------------------------

#define NV      40
#define TENC    8192
#define MAXLEN  200
#define EOS_IDX 38
#define NB      256
#define NT      1024
#define NW      16            /* waves per block */
#define ROWS    32            /* attention rows per block */
#define NG      16            /* out-logit accumulator groups */
#define SCALE   0.04419417382415922f  /* 1/sqrt(512) */

// ws layout (float indices)
#define WS_ARRIVE  16    /* int: cumulative barrier arrivals                 */
#define WS_ACC     128   /* float[3][NG][64]: per-group (40 logits + S@40)   */
#define WS_GH      4096  /* float[3][1536]: W_hh @ h + b_hh, 3-slot rotation */
#define WS_GI      8704  /* float[40*1536]: W_ih @ embed[v] + b_ih           */
// end: 8704 + 61440 = 70144 floats (~280 KiB)

__device__ __forceinline__ int ld_ai(int* p) {
  return __hip_atomic_load(p, __ATOMIC_RELAXED, __HIP_MEMORY_SCOPE_AGENT);
}
__device__ __forceinline__ float ld_af(float* p) {
  return __hip_atomic_load(p, __ATOMIC_RELAXED, __HIP_MEMORY_SCOPE_AGENT);
}
__device__ __forceinline__ void st_af(float* p, float v) {
  __hip_atomic_store(p, v, __ATOMIC_RELAXED, __HIP_MEMORY_SCOPE_AGENT);
}

__device__ __forceinline__ float wred(float s) {
#pragma unroll
  for (int o = 32; o > 0; o >>= 1) s += __shfl_xor(s, o, 64);
  return s;
}

// full-wave dot product of two 512-float vectors
__device__ __forceinline__ float wdot512(const float* __restrict__ a,
                                         const float* __restrict__ b) {
  const int l = threadIdx.x & 63;
  const float4 a0 = ((const float4*)a)[l];
  const float4 a1 = ((const float4*)a)[l + 64];
  const float4 b0 = ((const float4*)b)[l];
  const float4 b1 = ((const float4*)b)[l + 64];
  float s = a0.x * b0.x + a0.y * b0.y + a0.z * b0.z + a0.w * b0.w +
            a1.x * b1.x + a1.y * b1.y + a1.z * b1.z + a1.w * b1.w;
  return wred(s);
}

__global__ void dec_init(int* wsi) {
  const int tid = threadIdx.x + blockIdx.x * blockDim.x;
  if (tid < 4096) wsi[tid] = 0;  // control + acc slots
}

__global__ void __launch_bounds__(NT) dec_main(
    const float* __restrict__ enc, const float* __restrict__ hidden,
    const float* __restrict__ embed, const float* __restrict__ w_ih,
    const float* __restrict__ w_hh, const float* __restrict__ b_ih,
    const float* __restrict__ b_hh, const float* __restrict__ w_out,
    const float* __restrict__ b_out, float* __restrict__ o,
    float* __restrict__ ws) {
  const int b = blockIdx.x, tid = threadIdx.x;
  const int wave = tid >> 6, lane = tid & 63;
  int* wsi = (int*)ws;

  __shared__ __align__(16) float h_lds[512];
  __shared__ __align__(16) float sp_lds[1024];
  __shared__ float p_lds[ROWS];
  __shared__ float hp_lds[NV];   // W_out[:,512:].h + b_out (this block's copy)
  __shared__ float tmp_lds[64];  // decide scratch: colsums then logits
  __shared__ int best_lds;

  // ----------------- prologue -----------------
  if (tid < 512) h_lds[tid] = hidden[tid];
  if (tid == 0) best_lds = EOS_IDX;

  // gi_all[v][j] = W_ih[j].embed[v] + b_ih[j]  (240 dots per block)
  for (int u = wave; u < 240; u += NW) {
    const int g = b * 240 + u;
    const int v = g / 1536, j = g - v * 1536;
    const float d = wdot512(w_ih + (size_t)j * 512, embed + (size_t)v * 512);
    if (lane == 0) ws[WS_GI + (size_t)v * 1536 + j] = d + b_ih[j];
  }
  // gh(h0) into slot 2  (6 rows per block)
  for (int jr = wave; jr < 6; jr += NW) {
    const int j = b * 6 + jr;
    const float d = wdot512(w_hh + (size_t)j * 512, hidden);
    if (lane == 0) st_af(&ws[WS_GH + 2 * 1536 + j], d + b_hh[j]);
  }
  __syncthreads();  // drains vmcnt -> all stores at coherence point
  if (tid == 0)
    __hip_atomic_fetch_add(&wsi[WS_ARRIVE], 1, __ATOMIC_RELEASE,
                           __HIP_MEMORY_SCOPE_AGENT);

  // ----------------- main loop -----------------
  int eos_reg = -1;  // block0/tid0 only
  float* attn = o + (size_t)MAXLEN * NV + 1;
  const int r0 = b * ROWS;

  for (int t = 0; t < MAXLEN; ++t) {
    // single global barrier: wait for everyone's step-(t-1) publications
    if (tid == 0) {
      while (ld_ai(&wsi[WS_ARRIVE]) < NB * (t + 1)) __builtin_amdgcn_s_sleep(1);
    }
    __syncthreads();

    // prefetch gh (doesn't depend on best) to overlap the decide phase
    float ghr_r = 0.0f, ghz_r = 0.0f, ghn_r = 0.0f;
    if (tid < 512) {
      float* ghp = ws + WS_GH + ((t + 2) % 3) * 1536;
      ghr_r = ld_af(&ghp[tid]);
      ghz_r = ld_af(&ghp[tid + 512]);
      ghn_r = ld_af(&ghp[tid + 1024]);
    }

    // ---- decide step t-1 (redundant in every block) ----
    if (t > 0) {
      const int sd = (t - 1) % 3;
      if (tid < 48) {
        float s = 0.0f;
        float* a = ws + WS_ACC + sd * (NG * 64);
#pragma unroll
        for (int g = 0; g < NG; ++g) s += ld_af(&a[g * 64 + tid]);
        tmp_lds[tid] = s;
      }
      __syncthreads();
      const float S = tmp_lds[40];
      if (tid < NV) {
        const float ov = tmp_lds[tid] / S + hp_lds[tid];
        tmp_lds[tid] = ov;
        if (b == 0) o[(size_t)(t - 1) * NV + tid] = ov;
      }
      if (tid >= 64 && tid < 64 + ROWS) {  // wave 1: normalize prev attn
        const int i = tid - 64;
        attn[(size_t)(t - 1) * TENC + r0 + i] = p_lds[i] / S;
      }
      __syncthreads();
      if (tid == 0) {
        float bv = tmp_lds[0];
        int bi = 0;
#pragma unroll
        for (int v = 1; v < NV; ++v) {
          const float x = tmp_lds[v];
          if (x > bv) { bv = x; bi = v; }
        }
        best_lds = bi;
        if (b == 0 && bi == EOS_IDX && eos_reg < 0) eos_reg = t - 1;
      }
      __syncthreads();
    }

    // ---- GRU: h_t (redundant per block, dims 0..511) ----
    {
      const int best = best_lds;
      if (tid < 512) {
        const float* gi = ws + WS_GI + (size_t)best * 1536;
        const float gir = gi[tid], giz = gi[tid + 512], gin = gi[tid + 1024];
        const float r = 1.0f / (1.0f + expf(-(gir + ghr_r)));
        const float z = 1.0f / (1.0f + expf(-(giz + ghz_r)));
        const float n = tanhf(gin + r * ghn_r);
        h_lds[tid] = (1.0f - z) * n + z * h_lds[tid];
      }
    }
    __syncthreads();

    // ---- dots: attention (2/wave), gh (waves 0-5), hp (2-3/wave) ----
#pragma unroll
    for (int rr = wave; rr < ROWS; rr += NW) {
      const float d = wdot512(enc + (size_t)(r0 + rr) * 1024, h_lds);
      if (lane == 0) p_lds[rr] = expf(d * SCALE);
    }
    for (int jr = wave; jr < 6; jr += NW) {
      const int j = b * 6 + jr;
      const float d = wdot512(w_hh + (size_t)j * 512, h_lds);
      if (lane == 0) st_af(&ws[WS_GH + (t % 3) * 1536 + j], d + b_hh[j]);
    }
    for (int v = wave; v < NV; v += NW) {
      const float d = wdot512(w_out + (size_t)v * 1024 + 512, h_lds);
      if (lane == 0) hp_lds[v] = d + b_out[v];
    }
    __syncthreads();

    // ---- S partial + value pass ----
    if (tid == 0) {
      float s = 0.0f;
#pragma unroll
      for (int i = 0; i < ROWS; ++i) s += p_lds[i];
      atomicAdd(&ws[WS_ACC + (t % 3) * (NG * 64) + (b & (NG - 1)) * 64 + 40], s);
    }
    {
      const int c = tid & 511, rg = tid >> 9;  // 2 row-groups x 512 cols
      const float* vb = enc + 512 + (size_t)(r0 + rg * 16) * 1024;
      float a = 0.0f;
#pragma unroll
      for (int i = 0; i < 16; ++i)
        a += p_lds[rg * 16 + i] * vb[(size_t)i * 1024 + c];
      sp_lds[tid] = a;
    }
    __syncthreads();
    if (tid < 512) sp_lds[tid] += sp_lds[tid + 512];
    __syncthreads();

    // ---- fold summary through W_out[:, :512] into group accumulator ----
    for (int v = wave; v < NV; v += NW) {
      const float d = wdot512(w_out + (size_t)v * 1024, sp_lds);
      if (lane == 0)
        atomicAdd(&ws[WS_ACC + (t % 3) * (NG * 64) + (b & (NG - 1)) * 64 + v], d);
    }
    // zero slot (t+1)%3 (its readers all finished before barrier t-1)
    if (b < NG && tid < 48)
      st_af(&ws[WS_ACC + ((t + 1) % 3) * (NG * 64) + b * 64 + tid], 0.0f);
    __syncthreads();  // drains all vmcnt -> publications complete

    if (tid == 0)
      __hip_atomic_fetch_add(&wsi[WS_ARRIVE], 1, __ATOMIC_RELEASE,
                             __HIP_MEMORY_SCOPE_AGENT);
  }

  // ----------------- epilogue: decide step 199 -----------------
  if (tid == 0) {
    while (ld_ai(&wsi[WS_ARRIVE]) < NB * (MAXLEN + 1))
      __builtin_amdgcn_s_sleep(1);
  }
  __syncthreads();
  {
    const int sd = (MAXLEN - 1) % 3;
    if (tid < 48) {
      float s = 0.0f;
      float* a = ws + WS_ACC + sd * (NG * 64);
#pragma unroll
      for (int g = 0; g < NG; ++g) s += ld_af(&a[g * 64 + tid]);
      tmp_lds[tid] = s;
    }
    __syncthreads();
    const float S = tmp_lds[40];
    if (tid < NV) {
      const float ov = tmp_lds[tid] / S + hp_lds[tid];
      tmp_lds[tid] = ov;
      if (b == 0) o[(size_t)(MAXLEN - 1) * NV + tid] = ov;
    }
    if (tid >= 64 && tid < 64 + ROWS) {
      const int i = tid - 64;
      attn[(size_t)(MAXLEN - 1) * TENC + r0 + i] = p_lds[i] / S;
    }
    __syncthreads();
    if (b == 0 && tid == 0) {
      float bv = tmp_lds[0];
      int bi = 0;
#pragma unroll
      for (int v = 1; v < NV; ++v) {
        const float x = tmp_lds[v];
        if (x > bv) { bv = x; bi = v; }
      }
      if (bi == EOS_IDX && eos_reg < 0) eos_reg = MAXLEN - 1;
      o[(size_t)MAXLEN * NV] = (eos_reg < 0) ? (float)MAXLEN : (float)eos_reg;
    }
  }
}

extern "C" void kernel_launch(void* const* d_in, const int* in_sizes, int n_in,
                              void* d_out, int out_size, void* d_ws,
                              size_t ws_size, hipStream_t stream) {
  const float* enc    = (const float*)d_in[0];
  const float* hidden = (const float*)d_in[1];
  const float* embed  = (const float*)d_in[2];
  const float* w_ih   = (const float*)d_in[3];
  const float* w_hh   = (const float*)d_in[4];
  const float* b_ih   = (const float*)d_in[5];
  const float* b_hh   = (const float*)d_in[6];
  const float* w_out  = (const float*)d_in[7];
  const float* b_out  = (const float*)d_in[8];
  float* out = (float*)d_out;
  float* ws  = (float*)d_ws;

  dec_init<<<dim3(16), dim3(256), 0, stream>>>((int*)d_ws);
  dec_main<<<dim3(NB), dim3(NT), 0, stream>>>(enc, hidden, embed, w_ih, w_hh,
                                              b_ih, b_hh, w_out, b_out, out,
                                              ws);
}

// Round 3
// 1888.749 us; speedup vs baseline: 3.9810x; 2.4392x over previous
//
#include <hip/hip_runtime.h>
#include <math.h>

// ---------------------------------------------------------------------------
// TDS decoder R3: persistent kernel, 256 blocks x 1024 threads.
//  - M[i][v] = W_out[v,:512].V[i] precomputed per block in LDS: value pass
//    and summary fold replaced by a 40x32 LDS GEMV.
//  - hp (W_out[:,512:].h) distributed: blocks 1..40 compute one row each.
//  - Barrier = per-group (NG=32) accumulator lines with embedded release
//    counters; wave0 polls all 32 counters with ballot. No root counter.
//  - 4 __syncthreads per step; decide fused into wave0 (packed argmax).
// ---------------------------------------------------------------------------

#define NV      40
#define TENC    8192
#define MAXLEN  200
#define EOS_IDX 38
#define NB      256
#define NT      1024
#define NW      16
#define ROWS    32
#define NG      32                    /* accumulator groups (8 blocks each) */
#define GSTRIDE 96                    /* floats per group region            */
#define GCNT    64                    /* counter col (own cacheline)        */
#define HPOFF   (NG * GSTRIDE)        /* hp line within slot                */
#define SLOT    (NG * GSTRIDE + 64)   /* 3136 floats per rotation slot      */
#define SCALE   0.04419417382415922f  /* 1/sqrt(512) */

#define WS_ACC  128                   /* float[3][SLOT]                     */
#define WS_GH   9600                  /* float[3][1536]                     */
#define WS_GI   14208                 /* float[40*1536]                     */

__device__ __forceinline__ int ld_ai(int* p) {
  return __hip_atomic_load(p, __ATOMIC_RELAXED, __HIP_MEMORY_SCOPE_AGENT);
}
__device__ __forceinline__ float ld_af(float* p) {
  return __hip_atomic_load(p, __ATOMIC_RELAXED, __HIP_MEMORY_SCOPE_AGENT);
}
__device__ __forceinline__ void st_af(float* p, float v) {
  __hip_atomic_store(p, v, __ATOMIC_RELAXED, __HIP_MEMORY_SCOPE_AGENT);
}
__device__ __forceinline__ void st_ai(int* p, int v) {
  __hip_atomic_store(p, v, __ATOMIC_RELAXED, __HIP_MEMORY_SCOPE_AGENT);
}

__device__ __forceinline__ float wred(float s) {
#pragma unroll
  for (int o = 32; o > 0; o >>= 1) s += __shfl_xor(s, o, 64);
  return s;
}
__device__ __forceinline__ float dot8(float4 a0, float4 a1, float4 b0,
                                      float4 b1) {
  return a0.x * b0.x + a0.y * b0.y + a0.z * b0.z + a0.w * b0.w +
         a1.x * b1.x + a1.y * b1.y + a1.z * b1.z + a1.w * b1.w;
}
__device__ __forceinline__ float wdot512(const float* __restrict__ a,
                                         const float* __restrict__ b) {
  const int l = threadIdx.x & 63;
  const float4 a0 = ((const float4*)a)[l];
  const float4 a1 = ((const float4*)a)[l + 64];
  const float4 b0 = ((const float4*)b)[l];
  const float4 b1 = ((const float4*)b)[l + 64];
  return wred(dot8(a0, a1, b0, b1));
}

__global__ void dec_init(int* wsi) {
  for (int k = threadIdx.x; k < WS_GH; k += NT) wsi[k] = 0;
}

__global__ void __launch_bounds__(NT) dec_main(
    const float* __restrict__ enc, const float* __restrict__ hidden,
    const float* __restrict__ embed, const float* __restrict__ w_ih,
    const float* __restrict__ w_hh, const float* __restrict__ b_ih,
    const float* __restrict__ b_hh, const float* __restrict__ w_out,
    const float* __restrict__ b_out, float* __restrict__ o,
    float* __restrict__ ws) {
  const int b = blockIdx.x, tid = threadIdx.x;
  const int wave = tid >> 6, lane = tid & 63;
  const int g = b & (NG - 1);
  const int r0 = b * ROWS;

  __shared__ __align__(16) float h_lds[512];
  __shared__ float M_lds[32 * 41];  // padded stride 41: conflict-free
  __shared__ float p_lds[ROWS];
  __shared__ float sc_lds[1];
  __shared__ int best_lds;

  // ----------------- prologue -----------------
  if (tid < 512) h_lds[tid] = hidden[tid];
  if (tid == 0) best_lds = EOS_IDX;

  // gi_all[v][j] = W_ih[j].embed[v] + b_ih[j]  (distributed: 240/block)
  for (int u = wave; u < 240; u += NW) {
    const int gl = b * 240 + u;
    const int v = gl / 1536, j = gl - v * 1536;
    const float d = wdot512(w_ih + (size_t)j * 512, embed + (size_t)v * 512);
    if (lane == 0) ws[WS_GI + (size_t)v * 1536 + j] = d + b_ih[j];
  }
  // gh(h0) -> slot 2  (6 rows per block)
  for (int jr = wave; jr < 6; jr += NW) {
    const int j = b * 6 + jr;
    const float d = wdot512(w_hh + (size_t)j * 512, hidden);
    if (lane == 0) st_af(&ws[WS_GH + 2 * 1536 + j], d + b_hh[j]);
  }
  __syncthreads();  // drain
  if (tid == 0)
    __hip_atomic_fetch_add((int*)(ws + WS_ACC + 2 * SLOT + g * GSTRIDE + GCNT),
                           1, __ATOMIC_RELEASE, __HIP_MEMORY_SCOPE_AGENT);

  // M[i][v] = W_out[v,:512] . V[r0+i]  (block-local; overlaps stragglers)
  {
    const int i0 = wave * 2;
    const float* v0p = enc + (size_t)(r0 + i0) * 1024 + 512;
    const float* v1p = v0p + 1024;
    const float4 va0 = ((const float4*)v0p)[lane];
    const float4 va1 = ((const float4*)v0p)[lane + 64];
    const float4 vb0 = ((const float4*)v1p)[lane];
    const float4 vb1 = ((const float4*)v1p)[lane + 64];
    for (int v = 0; v < NV; ++v) {
      const float* wp = w_out + (size_t)v * 1024;
      const float4 w0 = ((const float4*)wp)[lane];
      const float4 w1 = ((const float4*)wp)[lane + 64];
      const float sa = wred(dot8(va0, va1, w0, w1));
      const float sb = wred(dot8(vb0, vb1, w0, w1));
      if (lane == 0) {
        M_lds[i0 * 41 + v] = sa;
        M_lds[(i0 + 1) * 41 + v] = sb;
      }
    }
  }

  // ----------------- main loop -----------------
  int eos_reg = -1;  // block0/wave0/lane0 only
  float* attn = o + (size_t)MAXLEN * NV + 1;

  for (int t = 0; t <= MAXLEN; ++t) {
    // ---- wave 0: poll all 32 group counters, then decide step t-1 ----
    if (wave == 0) {
      float* accs = ws + WS_ACC + ((t + 2) % 3) * SLOT;
      {
        int* cp = (int*)(accs + lane * GSTRIDE + GCNT);
        bool ok = (lane >= NG);
        while (true) {
          if (!ok) ok = (ld_ai(cp) >= 8);
          if (__ballot(!ok) == 0ull) break;
          __builtin_amdgcn_s_sleep(2);
        }
      }
      if (t > 0) {
        float cs = 0.0f;
        if (lane <= NV) {
#pragma unroll
          for (int gg = 0; gg < NG; ++gg) cs += ld_af(&accs[gg * GSTRIDE + lane]);
        }
        const float hp = (lane < NV) ? ld_af(&accs[HPOFF + lane]) : 0.0f;
        const float S = __shfl(cs, NV, 64);
        const float ov = cs * (1.0f / S) + hp;
        unsigned long long key = 0ull;
        if (lane < NV) {
          unsigned u = __float_as_uint(ov);
          u = (u & 0x80000000u) ? ~u : (u | 0x80000000u);
          key = ((unsigned long long)u << 32) | (unsigned)(~lane);
        }
#pragma unroll
        for (int m = 32; m > 0; m >>= 1) {
          const unsigned long long k2 = __shfl_xor(key, m, 64);
          if (k2 > key) key = k2;
        }
        const int best = (int)(~(unsigned)key);
        if (lane == 0) { best_lds = best; sc_lds[0] = S; }
        if (b == 0) {
          if (lane < NV) o[(size_t)(t - 1) * NV + lane] = ov;
          if (lane == 0) {
            if (best == EOS_IDX && eos_reg < 0) eos_reg = t - 1;
            if (t == MAXLEN)
              o[(size_t)MAXLEN * NV] =
                  (eos_reg < 0) ? (float)MAXLEN : (float)eos_reg;
          }
        }
      }
    }
    __syncthreads();  // barrier1: best_lds, sc_lds ready; globals ready

    // wave 1: normalize previous step's attention weights
    if (t > 0 && wave == 1 && lane < ROWS)
      attn[(size_t)(t - 1) * TENC + r0 + lane] =
          p_lds[lane] * (1.0f / sc_lds[0]);

    if (t == MAXLEN) break;

    // ---- waves 8-15: GRU combine h_t (gh from MALL, gi from L2) ----
    if (tid >= 512) {
      const int j = tid - 512;
      float* ghs = ws + WS_GH + ((t + 2) % 3) * 1536;
      const float ghr = ld_af(&ghs[j]);
      const float ghz = ld_af(&ghs[j + 512]);
      const float ghn = ld_af(&ghs[j + 1024]);
      const float* gi = ws + WS_GI + (size_t)best_lds * 1536;
      const float gir = gi[j], giz = gi[j + 512], gin = gi[j + 1024];
      const float r = 1.0f / (1.0f + expf(-(gir + ghr)));
      const float z = 1.0f / (1.0f + expf(-(giz + ghz)));
      const float n = tanhf(gin + r * ghn);
      h_lds[j] = (1.0f - z) * n + z * h_lds[j];
    }
    __syncthreads();  // barrier2: h_t ready

    // ---- dots ----
    {
      const float4 hh0 = ((const float4*)h_lds)[lane];
      const float4 hh1 = ((const float4*)h_lds)[lane + 64];
      {
        const float* k0p = enc + (size_t)(r0 + wave * 2) * 1024;
        const float* k1p = k0p + 1024;
        const float4 a0 = ((const float4*)k0p)[lane];
        const float4 a1 = ((const float4*)k0p)[lane + 64];
        const float4 c0 = ((const float4*)k1p)[lane];
        const float4 c1 = ((const float4*)k1p)[lane + 64];
        const float d0 = wred(dot8(a0, a1, hh0, hh1));
        const float d1 = wred(dot8(c0, c1, hh0, hh1));
        if (lane == 0) {
          p_lds[wave * 2] = expf(d0 * SCALE);
          p_lds[wave * 2 + 1] = expf(d1 * SCALE);
        }
      }
      if (wave < 6) {  // gh_t for step t+1 (6 rows/block, distributed)
        const int j = b * 6 + wave;
        const float* wp = w_hh + (size_t)j * 512;
        const float4 a0 = ((const float4*)wp)[lane];
        const float4 a1 = ((const float4*)wp)[lane + 64];
        const float d = wred(dot8(a0, a1, hh0, hh1));
        if (lane == 0) st_af(&ws[WS_GH + (t % 3) * 1536 + j], d + b_hh[j]);
      }
      if (wave == 6 && b >= 1 && b <= NV) {  // hp row (blocks 1..40)
        const int v = b - 1;
        const float* wp = w_out + (size_t)v * 1024 + 512;
        const float4 a0 = ((const float4*)wp)[lane];
        const float4 a1 = ((const float4*)wp)[lane + 64];
        const float d = wred(dot8(a0, a1, hh0, hh1));
        if (lane == 0)
          st_af(&ws[WS_ACC + (t % 3) * SLOT + HPOFF + v], d + b_out[v]);
      }
    }
    __syncthreads();  // barrier3: p_lds ready

    // ---- fold: S partial (wave0), p.M logits (waves 1-10), zero (wave11) ----
    {
      float* accsT = ws + WS_ACC + (t % 3) * SLOT;
      if (wave == 0) {
        float x = (lane < ROWS) ? p_lds[lane] : 0.0f;
        x = wred(x);
        if (lane == 0) atomicAdd(&accsT[g * GSTRIDE + NV], x);
      } else if (wave <= 10) {
#pragma unroll
        for (int q = 0; q < 4; ++q) {
          const int v = (wave - 1) * 4 + q;
          float x = (lane < ROWS) ? p_lds[lane] * M_lds[lane * 41 + v] : 0.0f;
          x = wred(x);
          if (lane == 0) atomicAdd(&accsT[g * GSTRIDE + v], x);
        }
      } else if (wave == 11 && b < NG) {
        float* nx = ws + WS_ACC + ((t + 1) % 3) * SLOT + b * GSTRIDE;
        if (lane <= NV) st_af(&nx[lane], 0.0f);
        if (lane == 41) st_ai((int*)&nx[GCNT], 0);
      }
    }
    __syncthreads();  // barrier4: drain all stores/atomics

    if (tid == 0)
      __hip_atomic_fetch_add(
          (int*)(ws + WS_ACC + (t % 3) * SLOT + g * GSTRIDE + GCNT), 1,
          __ATOMIC_RELEASE, __HIP_MEMORY_SCOPE_AGENT);
  }
}

extern "C" void kernel_launch(void* const* d_in, const int* in_sizes, int n_in,
                              void* d_out, int out_size, void* d_ws,
                              size_t ws_size, hipStream_t stream) {
  const float* enc    = (const float*)d_in[0];
  const float* hidden = (const float*)d_in[1];
  const float* embed  = (const float*)d_in[2];
  const float* w_ih   = (const float*)d_in[3];
  const float* w_hh   = (const float*)d_in[4];
  const float* b_ih   = (const float*)d_in[5];
  const float* b_hh   = (const float*)d_in[6];
  const float* w_out  = (const float*)d_in[7];
  const float* b_out  = (const float*)d_in[8];
  float* out = (float*)d_out;
  float* ws  = (float*)d_ws;

  dec_init<<<dim3(1), dim3(NT), 0, stream>>>((int*)d_ws);
  dec_main<<<dim3(NB), dim3(NT), 0, stream>>>(enc, hidden, embed, w_ih, w_hh,
                                              b_ih, b_hh, w_out, b_out, out,
                                              ws);
}

// Round 4
// 1512.681 us; speedup vs baseline: 4.9707x; 1.2486x over previous
//
#include <hip/hip_runtime.h>
#include <math.h>

// ---------------------------------------------------------------------------
// TDS decoder R4: persistent kernel, 256 blocks x 1024 threads.
//  - K rows, W_hh/W_out aux rows, and M columns live in REGISTERS (loaded
//    once): the per-step dot phase does zero L2 traffic for operands.
//  - LDS go/best flags replace barrier1: GRU gh MALL loads overlap wave0's
//    decide gather. Only 2 __syncthreads per step.
//  - Fold: per-wave partial (p0*M0+p1*M1) into LDS[16][48]; wave0 reduces and
//    pushes 41 atomics into 1 of NG=64 group regions + release counter RMW.
// ---------------------------------------------------------------------------

#define NV      40
#define TENC    8192
#define MAXLEN  200
#define EOS_IDX 38
#define NB      256
#define NT      1024
#define NW      16
#define ROWS    32
#define NG      64                    /* groups of NB/NG=4 blocks           */
#define GSTRIDE 96                    /* floats per group region            */
#define GCNT    64                    /* counter col (own cacheline)        */
#define HPOFF   (NG * GSTRIDE)        /* 6144: hp line within slot          */
#define SLOT    (HPOFF + 64)          /* 6208 floats per rotation slot      */
#define SCALE   0.04419417382415922f  /* 1/sqrt(512) */

#define WS_ACC  128                   /* float[3][SLOT]                     */
#define WS_GH   (WS_ACC + 3 * SLOT)   /* 18752: float[3][1536]              */
#define WS_GI   (WS_GH + 3 * 1536)    /* 23360: float[40*1536]              */

__device__ __forceinline__ int ld_ai(int* p) {
  return __hip_atomic_load(p, __ATOMIC_RELAXED, __HIP_MEMORY_SCOPE_AGENT);
}
__device__ __forceinline__ float ld_af(float* p) {
  return __hip_atomic_load(p, __ATOMIC_RELAXED, __HIP_MEMORY_SCOPE_AGENT);
}
__device__ __forceinline__ void st_af(float* p, float v) {
  __hip_atomic_store(p, v, __ATOMIC_RELAXED, __HIP_MEMORY_SCOPE_AGENT);
}
__device__ __forceinline__ void st_ai(int* p, int v) {
  __hip_atomic_store(p, v, __ATOMIC_RELAXED, __HIP_MEMORY_SCOPE_AGENT);
}
__device__ __forceinline__ int ld_lds_acq(int* p) {
  return __hip_atomic_load(p, __ATOMIC_ACQUIRE, __HIP_MEMORY_SCOPE_WORKGROUP);
}
__device__ __forceinline__ void st_lds_rel(int* p, int v) {
  __hip_atomic_store(p, v, __ATOMIC_RELEASE, __HIP_MEMORY_SCOPE_WORKGROUP);
}

__device__ __forceinline__ float wred(float s) {
#pragma unroll
  for (int o = 32; o > 0; o >>= 1) s += __shfl_xor(s, o, 64);
  return s;
}
__device__ __forceinline__ float dot8(float4 a0, float4 a1, float4 b0,
                                      float4 b1) {
  return a0.x * b0.x + a0.y * b0.y + a0.z * b0.z + a0.w * b0.w +
         a1.x * b1.x + a1.y * b1.y + a1.z * b1.z + a1.w * b1.w;
}
__device__ __forceinline__ float wdot512(const float* __restrict__ a,
                                         const float* __restrict__ b) {
  const int l = threadIdx.x & 63;
  const float4 a0 = ((const float4*)a)[l];
  const float4 a1 = ((const float4*)a)[l + 64];
  const float4 b0 = ((const float4*)b)[l];
  const float4 b1 = ((const float4*)b)[l + 64];
  return wred(dot8(a0, a1, b0, b1));
}

__global__ void dec_init(int* wsi) {
  for (int k = threadIdx.x; k < WS_GH; k += NT) wsi[k] = 0;
}

__global__ void __launch_bounds__(NT, 4) dec_main(
    const float* __restrict__ enc, const float* __restrict__ hidden,
    const float* __restrict__ embed, const float* __restrict__ w_ih,
    const float* __restrict__ w_hh, const float* __restrict__ b_ih,
    const float* __restrict__ b_hh, const float* __restrict__ w_out,
    const float* __restrict__ b_out, float* __restrict__ o,
    float* __restrict__ ws) {
  const int b = blockIdx.x, tid = threadIdx.x;
  const int wave = tid >> 6, lane = tid & 63;
  const int g = b & (NG - 1);
  const int r0 = b * ROWS;

  __shared__ __align__(16) float h_lds[512];
  __shared__ float pw_lds[NW * 48];
  __shared__ float sc_lds[1];
  __shared__ int go_lds;  // t+1 when step-t inputs are at the MALL
  __shared__ int bf_lds;  // (t<<6)|best

  // ----------------- prologue -----------------
  if (tid < 512) h_lds[tid] = hidden[tid];
  if (tid == 0) { go_lds = 0; bf_lds = -1; }

  // gi_all[v][j] = W_ih[j].embed[v] + b_ih[j]  (240 dots per block)
  for (int u = wave; u < 240; u += NW) {
    const int gl = b * 240 + u;
    const int v = gl / 1536, j = gl - v * 1536;
    const float d = wdot512(w_ih + (size_t)j * 512, embed + (size_t)v * 512);
    if (lane == 0) ws[WS_GI + (size_t)v * 1536 + j] = d + b_ih[j];
  }
  // gh(h0) -> slot 2  (waves 0-5, one row each)
  for (int jr = wave; jr < 6; jr += NW) {
    const int j = b * 6 + jr;
    const float d = wdot512(w_hh + (size_t)j * 512, hidden);
    if (lane == 0) st_af(&ws[WS_GH + 2 * 1536 + j], d + b_hh[j]);
  }
  __syncthreads();  // drain stores
  if (tid == 0)
    __hip_atomic_fetch_add((int*)(ws + WS_ACC + 2 * SLOT + g * GSTRIDE + GCNT),
                           1, __ATOMIC_RELEASE, __HIP_MEMORY_SCOPE_AGENT);

  // --- register-resident operands ---
  const float* k0p = enc + (size_t)(r0 + 2 * wave) * 1024;
  const float4 k0a = ((const float4*)k0p)[lane];
  const float4 k0b = ((const float4*)k0p)[lane + 64];
  const float4 k1a = ((const float4*)(k0p + 1024))[lane];
  const float4 k1b = ((const float4*)(k0p + 1024))[lane + 64];

  // M columns: Mr0/Mr1 = W_out[lane,:512].V[row0/1]; lane40 = 1 (S column)
  float Mr0 = (lane == 40) ? 1.0f : 0.0f, Mr1 = Mr0;
  {
    const float* v0p = k0p + 512;
    const float4 va0 = ((const float4*)v0p)[lane];
    const float4 va1 = ((const float4*)v0p)[lane + 64];
    const float4 vb0 = ((const float4*)(v0p + 1024))[lane];
    const float4 vb1 = ((const float4*)(v0p + 1024))[lane + 64];
    for (int v = 0; v < NV; ++v) {
      const float* wp = w_out + (size_t)v * 1024;
      const float4 w0 = ((const float4*)wp)[lane];
      const float4 w1 = ((const float4*)wp)[lane + 64];
      const float sa = wred(dot8(va0, va1, w0, w1));
      const float sb = wred(dot8(vb0, vb1, w0, w1));
      if (lane == v) { Mr0 = sa; Mr1 = sb; }
    }
  }
  // aux row: waves 1-6 -> W_hh row b*6+wave-1; wave 7 (b in 1..40) -> W_out hp
  float4 xa0 = {0, 0, 0, 0}, xa1 = {0, 0, 0, 0};
  float xb = 0.0f;
  if (wave >= 1 && wave <= 6) {
    const int j = b * 6 + (wave - 1);
    const float* wp = w_hh + (size_t)j * 512;
    xa0 = ((const float4*)wp)[lane];
    xa1 = ((const float4*)wp)[lane + 64];
    xb = b_hh[j];
  } else if (wave == 7 && b >= 1 && b <= NV) {
    const float* wp = w_out + (size_t)(b - 1) * 1024 + 512;
    xa0 = ((const float4*)wp)[lane];
    xa1 = ((const float4*)wp)[lane + 64];
    xb = b_out[b - 1];
  }

  // ----------------- main loop -----------------
  int eos_reg = -1;              // block0/wave0/lane0 only
  float p0 = 0.0f, p1 = 0.0f;    // this wave's attention weights (unnorm.)
  float* attn = o + (size_t)MAXLEN * NV + 1;

  for (int t = 0; t <= MAXLEN; ++t) {
    if (wave == 0) {
      float* accs = ws + WS_ACC + ((t + 2) % 3) * SLOT;
      {  // poll all NG counters (sticky per lane)
        int* cp = (int*)(accs + lane * GSTRIDE + GCNT);
        bool ok = false;
        for (;;) {
          if (!ok) ok = (ld_ai(cp) >= NB / NG);
          if (__ballot(!ok) == 0ull) break;
          __builtin_amdgcn_s_sleep(1);
        }
      }
      if (lane == 0) st_lds_rel(&go_lds, t + 1);  // GRU waves may start gh
      if (t > 0) {
        // gather 64 group partials (4 chains, all loads pipelined)
        float c0 = 0, c1 = 0, c2 = 0, c3 = 0;
#pragma unroll
        for (int q = 0; q < NG / 4; ++q) {
          c0 += ld_af(&accs[(4 * q + 0) * GSTRIDE + lane]);
          c1 += ld_af(&accs[(4 * q + 1) * GSTRIDE + lane]);
          c2 += ld_af(&accs[(4 * q + 2) * GSTRIDE + lane]);
          c3 += ld_af(&accs[(4 * q + 3) * GSTRIDE + lane]);
        }
        const float cs = (c0 + c1) + (c2 + c3);
        const float hp = (lane < NV) ? ld_af(&accs[HPOFF + lane]) : 0.0f;
        const float S = __shfl(cs, NV, 64);
        const float ov = cs * (1.0f / S) + hp;
        unsigned long long key = 0ull;
        if (lane < NV) {
          unsigned u = __float_as_uint(ov);
          u = (u & 0x80000000u) ? ~u : (u | 0x80000000u);
          key = ((unsigned long long)u << 32) | (unsigned)(~lane);
        }
#pragma unroll
        for (int m = 32; m > 0; m >>= 1) {
          const unsigned long long k2 = __shfl_xor(key, m, 64);
          if (k2 > key) key = k2;
        }
        const int best = (int)(~(unsigned)key);
        if (b == 0 && lane < NV) o[(size_t)(t - 1) * NV + lane] = ov;
        if (lane == 0) {
          sc_lds[0] = S;
          if (b == 0) {
            if (best == EOS_IDX && eos_reg < 0) eos_reg = t - 1;
            if (t == MAXLEN)
              o[(size_t)MAXLEN * NV] =
                  (eos_reg < 0) ? (float)MAXLEN : (float)eos_reg;
          }
          st_lds_rel(&bf_lds, (t << 6) | best);
        }
      } else if (lane == 0) {
        st_lds_rel(&bf_lds, EOS_IDX);  // (0<<6)|EOS
      }
    } else if (wave >= 8 && t < MAXLEN) {
      // ---- GRU waves: gh loads overlap wave0's decide ----
      const int j = tid - 512;
      while (ld_lds_acq(&go_lds) < t + 1) __builtin_amdgcn_s_sleep(1);
      float* ghs = ws + WS_GH + ((t + 2) % 3) * 1536;
      const float ghr = ld_af(&ghs[j]);
      const float ghz = ld_af(&ghs[j + 512]);
      const float ghn = ld_af(&ghs[j + 1024]);
      int bf;
      while (((bf = ld_lds_acq(&bf_lds)) >> 6) < t) __builtin_amdgcn_s_sleep(1);
      const float* gi = ws + WS_GI + (size_t)(bf & 63) * 1536;
      const float gir = gi[j], giz = gi[j + 512], gin = gi[j + 1024];
      const float r = 1.0f / (1.0f + expf(-(gir + ghr)));
      const float z = 1.0f / (1.0f + expf(-(giz + ghz)));
      const float n = tanhf(gin + r * ghn);
      h_lds[j] = (1.0f - z) * n + z * h_lds[j];
    }
    __syncthreads();  // barrier A: h_t, sc_lds ready

    // store previous step's normalized attention weights (p in regs)
    if (t > 0 && lane < 2)
      attn[(size_t)(t - 1) * TENC + r0 + 2 * wave + lane] =
          (lane ? p1 : p0) * (1.0f / sc_lds[0]);
    if (t == MAXLEN) break;

    // ---- dots: all operands in registers / LDS ----
    {
      const float4 hh0 = ((const float4*)h_lds)[lane];
      const float4 hh1 = ((const float4*)h_lds)[lane + 64];
      const float d0 = wred(dot8(k0a, k0b, hh0, hh1));
      const float d1 = wred(dot8(k1a, k1b, hh0, hh1));
      p0 = expf(d0 * SCALE);
      p1 = expf(d1 * SCALE);
      if (lane < 41) pw_lds[wave * 48 + lane] = p0 * Mr0 + p1 * Mr1;
      if (wave >= 1 && wave <= 6) {  // gh_t row for step t+1
        const float d = wred(dot8(xa0, xa1, hh0, hh1));
        if (lane == 0)
          st_af(&ws[WS_GH + (t % 3) * 1536 + b * 6 + (wave - 1)], d + xb);
      } else if (wave == 7 && b >= 1 && b <= NV) {  // hp row
        const float d = wred(dot8(xa0, xa1, hh0, hh1));
        if (lane == 0)
          st_af(&ws[WS_ACC + (t % 3) * SLOT + HPOFF + (b - 1)], d + xb);
      } else if (wave == 15 && b < NG) {  // zero slot (t+1)%3 group b
        float* nx = ws + WS_ACC + ((t + 1) % 3) * SLOT + b * GSTRIDE;
        if (lane < 41) st_af(&nx[lane], 0.0f);
        else if (lane == 41) st_ai((int*)&nx[GCNT], 0);
      }
    }
    __syncthreads();  // barrier C: pw complete, all stores drained

    // ---- wave0: reduce 16 wave-partials, push, release counter ----
    if (wave == 0) {
      float* accsT = ws + WS_ACC + (t % 3) * SLOT;
      if (lane < 41) {
        float s = 0.0f;
#pragma unroll
        for (int w2 = 0; w2 < NW; ++w2) s += pw_lds[w2 * 48 + lane];
        atomicAdd(&accsT[g * GSTRIDE + lane], s);
      }
      if (lane == 0)
        __hip_atomic_fetch_add((int*)(accsT + g * GSTRIDE + GCNT), 1,
                               __ATOMIC_RELEASE, __HIP_MEMORY_SCOPE_AGENT);
    }
  }
}

extern "C" void kernel_launch(void* const* d_in, const int* in_sizes, int n_in,
                              void* d_out, int out_size, void* d_ws,
                              size_t ws_size, hipStream_t stream) {
  const float* enc    = (const float*)d_in[0];
  const float* hidden = (const float*)d_in[1];
  const float* embed  = (const float*)d_in[2];
  const float* w_ih   = (const float*)d_in[3];
  const float* w_hh   = (const float*)d_in[4];
  const float* b_ih   = (const float*)d_in[5];
  const float* b_hh   = (const float*)d_in[6];
  const float* w_out  = (const float*)d_in[7];
  const float* b_out  = (const float*)d_in[8];
  float* out = (float*)d_out;
  float* ws  = (float*)d_ws;

  dec_init<<<dim3(1), dim3(NT), 0, stream>>>((int*)d_ws);
  dec_main<<<dim3(NB), dim3(NT), 0, stream>>>(enc, hidden, embed, w_ih, w_hh,
                                              b_ih, b_hh, w_out, b_out, out,
                                              ws);
}